// Round 1
// 773.522 us; speedup vs baseline: 1.0009x; 1.0009x over previous
//
#include <hip/hip_runtime.h>
#include <stdint.h>

#define NN 50000   // nodes
#define NE 100000  // edges
#define DD 768     // feature dim
#define KC 1536    // concatenated K = 2*DD
#define SCAN_B 196 // ceil(NN/256)
#define NTM 391    // ceil(NN/128)
#define NTN 6      // DD/128

typedef __attribute__((ext_vector_type(8))) __bf16 bf16x8;
typedef __attribute__((ext_vector_type(4))) float floatx4;

static __device__ __forceinline__ float bf2f(unsigned short u) {
    union { unsigned int u; float f; } c; c.u = ((unsigned int)u) << 16; return c.f;
}
static __device__ __forceinline__ unsigned short f2bf(float f) {
    union { float f; unsigned int u; } c; c.f = f;
    return (unsigned short)((c.u + 0x7FFFu + ((c.u >> 16) & 1u)) >> 16);
}

// async global->LDS, 16B per lane; LDS dst = wave-uniform base + lane*16
static __device__ __forceinline__ void gld16(const void* g, void* l) {
    __builtin_amdgcn_global_load_lds(
        (const __attribute__((address_space(1))) unsigned int*)g,
        (__attribute__((address_space(3))) unsigned int*)l, 16, 0, 0);
}

// ---------------- prep kernels ----------------

// x (f32) -> bf16 into right half of Acat1 ([n][768..1535])
__global__ __launch_bounds__(192) void k_convert_x(const float* __restrict__ x,
                                                   unsigned short* __restrict__ acat) {
    const int n = blockIdx.x;
    const int c = threadIdx.x * 4;
    const float4 v = *(const float4*)(x + (size_t)n * DD + c);
    ushort4 o;
    o.x = f2bf(v.x); o.y = f2bf(v.y); o.z = f2bf(v.z); o.w = f2bf(v.w);
    *(ushort4*)(acat + (size_t)n * KC + DD + c) = o;
}

// Bcat[layer][j][k] = k<768 ? Wl[j][k] : Wr[j][k-768]   (bf16)
__global__ __launch_bounds__(384) void k_convert_w(const float* __restrict__ W1l,
                                                   const float* __restrict__ W1r,
                                                   const float* __restrict__ W2l,
                                                   const float* __restrict__ W2r,
                                                   unsigned short* __restrict__ B1,
                                                   unsigned short* __restrict__ B2) {
    const int j = blockIdx.x;
    const int layer = blockIdx.y;
    const int k = threadIdx.x * 4;
    const float* Wl = layer ? W2l : W1l;
    const float* Wr = layer ? W2r : W1r;
    unsigned short* B = layer ? B2 : B1;
    const float4 v = (k < DD) ? *(const float4*)(Wl + (size_t)j * DD + k)
                              : *(const float4*)(Wr + (size_t)j * DD + (k - DD));
    ushort4 o; o.x = f2bf(v.x); o.y = f2bf(v.y); o.z = f2bf(v.z); o.w = f2bf(v.w);
    *(ushort4*)(B + (size_t)j * KC + k) = o;
}

// ---------------- CSR build (by dst) ----------------

__global__ __launch_bounds__(256) void k_hist(const int* __restrict__ dst,
                                              int* __restrict__ cnt) {
    int e = blockIdx.x * 256 + threadIdx.x;
    if (e < NE) atomicAdd(&cnt[dst[e]], 1);
}

// hierarchical scan, stage 1: per-block inclusive scan of 256-elem chunks
__global__ __launch_bounds__(256) void k_scan1(const int* __restrict__ cnt,
                                               int* __restrict__ rowptr,
                                               int* __restrict__ partial) {
    __shared__ int buf[256];
    const int t = threadIdx.x;
    const int i = blockIdx.x * 256 + t;
    int v = (i < NN) ? cnt[i] : 0;
    buf[t] = v;
    __syncthreads();
#pragma unroll
    for (int off = 1; off < 256; off <<= 1) {
        int u = (t >= off) ? buf[t - off] : 0;
        __syncthreads();
        buf[t] += u;
        __syncthreads();
    }
    if (i < NN) rowptr[i + 1] = buf[t];
    if (t == 255) partial[blockIdx.x] = buf[255];
}

// stage 2: single block, exclusive scan of SCAN_B partials
__global__ __launch_bounds__(256) void k_scan2(int* __restrict__ partial) {
    __shared__ int buf[256];
    const int t = threadIdx.x;
    int v = (t < SCAN_B) ? partial[t] : 0;
    buf[t] = v;
    __syncthreads();
#pragma unroll
    for (int off = 1; off < 256; off <<= 1) {
        int u = (t >= off) ? buf[t - off] : 0;
        __syncthreads();
        buf[t] += u;
        __syncthreads();
    }
    if (t < SCAN_B) partial[t] = buf[t] - v;  // exclusive
}

// stage 3: add block offsets, set rowptr[0]
__global__ __launch_bounds__(256) void k_scan3(int* __restrict__ rowptr,
                                               const int* __restrict__ partial) {
    const int i = blockIdx.x * 256 + threadIdx.x;
    if (i < NN) rowptr[i + 1] += partial[blockIdx.x];
    if (i == 0) rowptr[0] = 0;
}

__global__ __launch_bounds__(256) void k_fill(const int* __restrict__ src,
                                              const int* __restrict__ dst,
                                              const int* __restrict__ rowptr,
                                              int* __restrict__ cursor,
                                              int* __restrict__ esrc) {
    int e = blockIdx.x * 256 + threadIdx.x;
    if (e < NE) {
        const int d = dst[e];
        const int pos = atomicAdd(&cursor[d], 1);
        esrc[rowptr[d] + pos] = src[e];
    }
}

// ---------------- aggregation by gather (no atomics) ----------------
// gather bf16 rows from right half of srcmat, mean in f32, write bf16 left half of dstmat
__global__ __launch_bounds__(192) void k_agg(const unsigned short* __restrict__ srcmat,
                                             const int* __restrict__ rowptr,
                                             const int* __restrict__ esrc,
                                             unsigned short* __restrict__ dstmat) {
    const int n = blockIdx.x;
    const int c = threadIdx.x * 4;
    const int beg = rowptr[n], end = rowptr[n + 1];
    float4 a = {0.f, 0.f, 0.f, 0.f};
    for (int e = beg; e < end; ++e) {
        const int s = esrc[e];
        const ushort4 v = *(const ushort4*)(srcmat + (size_t)s * KC + DD + c);
        a.x += bf2f(v.x); a.y += bf2f(v.y); a.z += bf2f(v.z); a.w += bf2f(v.w);
    }
    const float inv = (end > beg) ? 1.0f / (float)(end - beg) : 1.0f;
    ushort4 o;
    o.x = f2bf(a.x * inv); o.y = f2bf(a.y * inv);
    o.z = f2bf(a.z * inv); o.w = f2bf(a.w * inv);
    *(ushort4*)(dstmat + (size_t)n * KC + c) = o;
}

// ---------------- GEMM: C[M x 768] = A[M x 1536] * B[768 x 1536]^T + bias ----
// 128x128 tile, double-buffered LDS, prefetch-next-before-compute (T3 minimum
// 2-phase recipe): STAGE(kt+1) issues before ds_read+MFMA of kt; the single
// __syncthreads per K-step performs the vmcnt(0) drain AFTER compute covered
// most of the load latency (previous version drained immediately after issue).
// Block mapping: tn-fast logical order + bijective XCD chunking (m204) so the
// 6 tn-tiles sharing one A-tile run adjacently on ONE XCD -> A fetched once
// from HBM, 6x reuse from that XCD's L2.
// MODE 0: +bias, relu, store bf16 into right half of Acat2
// MODE 1: +bias, store f32 to out
template <int MODE>
__global__ __launch_bounds__(256) void k_gemm(const unsigned short* __restrict__ A,
                                              const unsigned short* __restrict__ B,
                                              const float* __restrict__ bias,
                                              unsigned short* __restrict__ outA,
                                              float* __restrict__ outF) {
    __shared__ alignas(16) unsigned short sA[2][128 * 32];
    __shared__ alignas(16) unsigned short sB[2][128 * 32];
    const int tid = threadIdx.x;
    const int w = tid >> 6, lane = tid & 63;
    const int quad = lane >> 4, r16 = lane & 15;
    const int wm = (w & 1) * 64, wn = (w >> 1) * 64;

    // bijective XCD-aware remap (m204): xcd = wgid & 7 gets contiguous logical range
    const int nwg = NTM * NTN;
    const int q = nwg >> 3, r = nwg & 7;
    const int xcd = blockIdx.x & 7, slot = blockIdx.x >> 3;
    const int L = (xcd < r ? xcd * (q + 1) : r * (q + 1) + (xcd - r) * q) + slot;
    const int tn = L % NTN;   // fast: 6 consecutive L share one A-tile
    const int tm = L / NTN;
    const int rowBase = tm * 128;

    floatx4 acc[4][4];
#pragma unroll
    for (int i = 0; i < 4; ++i)
#pragma unroll
        for (int j = 0; j < 4; ++j) acc[i][j] = (floatx4){0.f, 0.f, 0.f, 0.f};

    // stage one 32-wide K-slice of A and B into LDS buffer `buf`
    auto stage = [&](int buf, int kt) {
        const int k0 = kt * 32;
#pragma unroll
        for (int qq = 0; qq < 2; ++qq) {
            const int c0 = (w * 2 + qq) * 64;
            const int c = c0 + lane;
            const int row = c >> 2;
            const int col = (c & 3) * 8;
            int gr = rowBase + row; if (gr > NN - 1) gr = NN - 1;  // clamp tail tile
            gld16(A + (size_t)gr * KC + k0 + col, &sA[buf][(size_t)c0 * 8]);
            gld16(B + (size_t)(tn * 128 + row) * KC + k0 + col, &sB[buf][(size_t)c0 * 8]);
        }
    };

    const int nk = KC / 32;  // 48
    int cur = 0;
    stage(0, 0);
    __syncthreads();  // drains vmcnt(0): tile 0 resident

    for (int kt = 0; kt < nk; ++kt) {
        if (kt + 1 < nk) stage(cur ^ 1, kt + 1);  // issue next-tile loads FIRST
        bf16x8 af[4], bfr[4];
#pragma unroll
        for (int i = 0; i < 4; ++i)
            af[i] = *(const bf16x8*)(&sA[cur][(wm + i * 16 + r16) * 32 + quad * 8]);
#pragma unroll
        for (int j = 0; j < 4; ++j)
            bfr[j] = *(const bf16x8*)(&sB[cur][(wn + j * 16 + r16) * 32 + quad * 8]);
#pragma unroll
        for (int i = 0; i < 4; ++i)
#pragma unroll
            for (int j = 0; j < 4; ++j)
                acc[i][j] = __builtin_amdgcn_mfma_f32_16x16x32_bf16(af[i], bfr[j], acc[i][j], 0, 0, 0);
        // single barrier per K-step: implicit vmcnt(0) drain of the prefetch
        // happens here, AFTER ds_read+MFMA covered the load latency; also
        // guarantees all waves finished reading buf[cur] before it is
        // overwritten in the next iteration.
        __syncthreads();
        cur ^= 1;
    }

    // epilogue: C/D layout col=lane&15, row=quad*4+reg
#pragma unroll
    for (int i = 0; i < 4; ++i)
#pragma unroll
        for (int j = 0; j < 4; ++j) {
            const int gcol = tn * 128 + wn + j * 16 + r16;
            const float bv = bias[gcol];
#pragma unroll
            for (int rr = 0; rr < 4; ++rr) {
                const int grow = rowBase + wm + i * 16 + quad * 4 + rr;
                if (grow < NN) {
                    float v = acc[i][j][rr] + bv;
                    if (MODE == 0) {
                        v = fmaxf(v, 0.0f);
                        outA[(size_t)grow * KC + DD + gcol] = f2bf(v);
                    } else {
                        outF[(size_t)grow * DD + gcol] = v;
                    }
                }
            }
        }
}

extern "C" void kernel_launch(void* const* d_in, const int* in_sizes, int n_in,
                              void* d_out, int out_size, void* d_ws, size_t ws_size,
                              hipStream_t stream) {
    const float* x   = (const float*)d_in[0];
    const int*   ei  = (const int*)d_in[1];
    const float* W1l = (const float*)d_in[2];
    const float* b1l = (const float*)d_in[3];
    const float* W1r = (const float*)d_in[4];
    const float* W2l = (const float*)d_in[5];
    const float* b2l = (const float*)d_in[6];
    const float* W2r = (const float*)d_in[7];
    const int* src = ei;
    const int* dst = ei + NE;
    float* out = (float*)d_out;

    // ws layout (~310 MB):
    //   Acat1: [N x 1536] bf16  (left=agg1, right=bf16(x))
    //   Acat2: [N x 1536] bf16  (left=agg2, right=h)
    //   B1,B2: [768 x 1536] bf16 each
    //   CSR:   cnt[N] (reused as cursor), rowptr[N+1], esrc[E], partial[SCAN_B]
    char* ws = (char*)d_ws;
    unsigned short* Acat1 = (unsigned short*)ws;
    unsigned short* Acat2 = (unsigned short*)(ws + (size_t)NN * KC * 2);
    unsigned short* B1    = (unsigned short*)(ws + (size_t)NN * KC * 4);
    unsigned short* B2    = B1 + (size_t)DD * KC;
    int* cnt    = (int*)(ws + (size_t)NN * KC * 4 + (size_t)DD * KC * 4);
    int* rowptr = cnt + NN;
    int* esrc   = rowptr + NN + 1;
    int* partial = esrc + NE;

    // CSR build (hierarchical scan; no single-block serialization)
    hipMemsetAsync(cnt, 0, NN * sizeof(int), stream);
    k_hist<<<(NE + 255) / 256, 256, 0, stream>>>(dst, cnt);
    k_scan1<<<SCAN_B, 256, 0, stream>>>(cnt, rowptr, partial);
    k_scan2<<<1, 256, 0, stream>>>(partial);
    k_scan3<<<SCAN_B, 256, 0, stream>>>(rowptr, partial);
    hipMemsetAsync(cnt, 0, NN * sizeof(int), stream);  // reuse as cursor
    k_fill<<<(NE + 255) / 256, 256, 0, stream>>>(src, dst, rowptr, cnt, esrc);

    // converts
    k_convert_x<<<NN, 192, 0, stream>>>(x, Acat1);
    dim3 wgrid(DD, 2);
    k_convert_w<<<wgrid, 384, 0, stream>>>(W1l, W1r, W2l, W2r, B1, B2);

    const int ggrid = NTM * NTN;  // 1D grid, XCD-chunked tn-fast mapping inside kernel

    // layer 1 (aggregate bf16(x) from right half of Acat1)
    k_agg<<<NN, 192, 0, stream>>>(Acat1, rowptr, esrc, Acat1);
    k_gemm<0><<<ggrid, 256, 0, stream>>>(Acat1, B1, b1l, Acat2, nullptr);

    // layer 2
    k_agg<<<NN, 192, 0, stream>>>(Acat2, rowptr, esrc, Acat2);
    k_gemm<1><<<ggrid, 256, 0, stream>>>(Acat2, B2, b2l, nullptr, out);
}